// Round 1
// baseline (126.522 us; speedup 1.0000x reference)
//
#include <hip/hip_runtime.h>
#include <hip/hip_bf16.h>
#include <cstddef>

// ---------------------------------------------------------------------------
// Problem dims: B=16, N=4, S=64, K=50, VD=1024, QD=768, H=512
//   v_proj[b,k,h]   = v[b,0,k,:]   . Wv[h,:] + bv[h]     (M1=800,  K=1024, N=512)
//   q_proj[b,n,s,h] = q[b,n,s,0,:] . Wq[h,:] + bq[h]     (M2=4096, K=768,  N=512)
//   logits[row,k]   = sum_h Wl[h] * tanh(vp[k,h] + qp[row,h])   (+bl, softmax-invariant)
//   out = masked softmax over k (50 boxes)
// ---------------------------------------------------------------------------

typedef __attribute__((ext_vector_type(4))) float  f32x4;
typedef __attribute__((ext_vector_type(8))) short  bfrag;   // 8 bf16 = 4 VGPRs
typedef __attribute__((ext_vector_type(4))) unsigned short u16x4;

__device__ __forceinline__ void gload16(const void* g, void* l) {
  __builtin_amdgcn_global_load_lds((const __attribute__((address_space(1))) void*)g,
                                   (__attribute__((address_space(3))) void*)l, 16, 0, 0);
}

__device__ __forceinline__ unsigned short f2bf(float f) {
  unsigned int u = __float_as_uint(f);
  u = (u + 0x7FFFu + ((u >> 16) & 1u)) >> 16;   // RTN-even; inputs finite
  return (unsigned short)u;
}

// ---------------------------------------------------------------------------
// fp32 -> bf16 conversion of v, Wv, q, Wq (single fused kernel, float4 granularity)
// segments (in float4 units): v 204800 | Wv 131072 | q 786432 | Wq 98304
// ---------------------------------------------------------------------------
__global__ void __launch_bounds__(256) cvt_all(
    const float* __restrict__ v, const float* __restrict__ wv,
    const float* __restrict__ q, const float* __restrict__ wq,
    unsigned short* __restrict__ vb, unsigned short* __restrict__ wvb,
    unsigned short* __restrict__ qb, unsigned short* __restrict__ wqb) {
  const int total = 1220608;
  for (int f = blockIdx.x * 256 + threadIdx.x; f < total; f += gridDim.x * 256) {
    const float* src; unsigned short* dst; int off;
    if (f < 204800)       { src = v;  dst = vb;  off = f; }
    else if (f < 335872)  { src = wv; dst = wvb; off = f - 204800; }
    else if (f < 1122304) { src = q;  dst = qb;  off = f - 335872; }
    else                  { src = wq; dst = wqb; off = f - 1122304; }
    f32x4 x = ((const f32x4*)src)[off];
    u16x4 o;
    o[0] = f2bf(x[0]); o[1] = f2bf(x[1]); o[2] = f2bf(x[2]); o[3] = f2bf(x[3]);
    ((u16x4*)dst)[off] = o;
  }
}

// ---------------------------------------------------------------------------
// bf16 GEMM: C[M,N] = A[M,Kd] * W[N,Kd]^T + bias[N], fp32 out.
// Tile 128(M) x 64(N), BK=32. 256 threads = 4 waves (2x2), wave tile 64x32.
// global_load_lds width-16 staging, m97-style 2-barrier loop.
// ---------------------------------------------------------------------------
__global__ void __launch_bounds__(256) gemm_bt(
    const unsigned short* __restrict__ A, const unsigned short* __restrict__ W,
    const float* __restrict__ bias, float* __restrict__ C,
    int M, int Kd, int Nd) {
  __shared__ unsigned short As[128 * 32];   // [row][k] linear
  __shared__ unsigned short Bs[64 * 32];

  const int t    = threadIdx.x;
  const int lane = t & 63;
  const int wave = t >> 6;
  const int wm   = wave >> 1;      // 0..1
  const int wn   = wave & 1;       // 0..1
  const int la   = lane & 15;      // frag row/col
  const int lb   = lane >> 4;      // k-group (0..3)
  const int m0   = blockIdx.y * 128;
  const int n0   = blockIdx.x * 64;

  f32x4 acc[4][2] = {};

  for (int k0 = 0; k0 < Kd; k0 += 32) {
    __syncthreads();
    // stage A tile: 128 rows x 32 bf16 = 8KB = 512 x 16B chunks
#pragma unroll
    for (int i = 0; i < 2; ++i) {
      int c   = i * 256 + t;
      int row = c >> 2;
      int kk  = (c & 3) * 8;
      int gr  = m0 + row; if (gr >= M) gr = M - 1;   // clamp (store-side guarded)
      gload16(A + (size_t)gr * Kd + k0 + kk, (char*)As + c * 16);
    }
    // stage B tile: 64 x 32 = 4KB = 256 chunks
    {
      int row = t >> 2;
      int kk  = (t & 3) * 8;
      gload16(W + (size_t)(n0 + row) * Kd + k0 + kk, (char*)Bs + t * 16);
    }
    __syncthreads();

    bfrag a[4], b[2];
#pragma unroll
    for (int r = 0; r < 4; ++r)
      a[r] = *(const bfrag*)&As[(wm * 64 + r * 16 + la) * 32 + lb * 8];
#pragma unroll
    for (int c = 0; c < 2; ++c)
      b[c] = *(const bfrag*)&Bs[(wn * 32 + c * 16 + la) * 32 + lb * 8];
#pragma unroll
    for (int r = 0; r < 4; ++r)
#pragma unroll
      for (int c = 0; c < 2; ++c)
        acc[r][c] = __builtin_amdgcn_mfma_f32_16x16x32_bf16(a[r], b[c], acc[r][c], 0, 0, 0);
  }

  // epilogue: D lane layout col = lane&15, row = (lane>>4)*4 + reg
#pragma unroll
  for (int c = 0; c < 2; ++c) {
    int col = n0 + wn * 32 + c * 16 + la;
    float bcol = bias[col];
#pragma unroll
    for (int r = 0; r < 4; ++r) {
      int mbase = m0 + wm * 64 + r * 16 + lb * 4;
#pragma unroll
      for (int e = 0; e < 4; ++e) {
        int mr = mbase + e;
        if (mr < M) C[(size_t)mr * Nd + col] = acc[r][c][e] + bcol;
      }
    }
  }
}

// ---------------------------------------------------------------------------
// Stage 3: logits + masked softmax, fused.
// grid (16 chunks, 16 b), 256 threads. Each block: 16 rows x 50 k x 512 h.
// Thread (row = t&15, g = t>>4) owns k = g + 16j, j=0..3 (k<50).
// h streamed in LDS chunks of 64 (vp rows padded to 68 -> conflict-free).
// ---------------------------------------------------------------------------
__global__ void __launch_bounds__(256) stage3_kernel(
    const float* __restrict__ vp, const float* __restrict__ qp,
    const float* __restrict__ wl, const int* __restrict__ box_mask,
    float* __restrict__ out) {
  __shared__ float vpS[50][68];
  __shared__ float qpS[16][68];
  __shared__ float wlS[68];
  __shared__ float logitsS[16][52];

  const int b     = blockIdx.y;
  const int chunk = blockIdx.x;
  const int t     = threadIdx.x;
  const int row   = t & 15;
  const int g     = t >> 4;
  const int rowg0 = chunk * 16;

  const float CEXP = 2.885390081777927f;   // 2*log2(e)

  float acc[4] = {0.f, 0.f, 0.f, 0.f};

  for (int h0 = 0; h0 < 512; h0 += 64) {
    __syncthreads();
    // stage vp chunk: 50*16 = 800 float4s
    for (int f = t; f < 800; f += 256) {
      int k = f >> 4, hh = (f & 15) << 2;
      *(f32x4*)&vpS[k][hh] = *(const f32x4*)&vp[(size_t)(b * 50 + k) * 512 + h0 + hh];
    }
    // stage qp chunk: 16 rows x 64 = 256 float4s (1 per thread)
    {
      int r = t >> 4, hh = (t & 15) << 2;
      *(f32x4*)&qpS[r][hh] = *(const f32x4*)&qp[(size_t)(b * 256 + rowg0 + r) * 512 + h0 + hh];
    }
    if (t < 16) *(f32x4*)&wlS[t * 4] = *(const f32x4*)&wl[h0 + t * 4];
    __syncthreads();

    for (int hh = 0; hh < 64; hh += 4) {
      f32x4 q4 = *(const f32x4*)&qpS[row][hh];
      f32x4 w4 = *(const f32x4*)&wlS[hh];
#pragma unroll
      for (int j = 0; j < 4; ++j) {
        int k = g + 16 * j;
        if (k < 50) {
          f32x4 v4 = *(const f32x4*)&vpS[k][hh];
#pragma unroll
          for (int e = 0; e < 4; ++e) {
            float x  = v4[e] + q4[e];
            float ex = __builtin_amdgcn_exp2f(x * CEXP);
            float rc = __builtin_amdgcn_rcpf(ex + 1.0f);
            float th = fmaf(-2.0f, rc, 1.0f);            // tanh(x)
            acc[j] = fmaf(w4[e], th, acc[j]);
          }
        }
      }
    }
  }

  // gather logits into LDS
#pragma unroll
  for (int j = 0; j < 4; ++j) {
    int k = g + 16 * j;
    if (k < 50) logitsS[row][k] = acc[j];
  }
  __syncthreads();

  // masked softmax over k (exactly mirrors reference: where(mask, l, -1e9))
  if (t < 16) {
    const int r = t;
    float mx = -3.4e38f;
    for (int k = 0; k < 50; ++k) {
      float l = logitsS[r][k];
      l = (box_mask[b * 50 + k] > 0) ? l : -1e9f;
      logitsS[r][k] = l;
      mx = fmaxf(mx, l);
    }
    float s = 0.f;
    for (int k = 0; k < 50; ++k) {
      float e = __builtin_amdgcn_exp2f((logitsS[r][k] - mx) * 1.4426950408889634f);
      logitsS[r][k] = e;
      s += e;
    }
    float inv = 1.0f / s;
    float* orow = out + (size_t)(b * 256 + rowg0 + r) * 50;
    for (int k = 0; k < 50; ++k) orow[k] = logitsS[r][k] * inv;
  }
}

// ---------------------------------------------------------------------------
// launch
// ---------------------------------------------------------------------------
extern "C" void kernel_launch(void* const* d_in, const int* in_sizes, int n_in,
                              void* d_out, int out_size, void* d_ws, size_t ws_size,
                              hipStream_t stream) {
  const float* v        = (const float*)d_in[0];
  const float* q        = (const float*)d_in[1];
  const int*   box_mask = (const int*)d_in[2];
  // d_in[3] = tags_attention (unused by reference)
  const float* Wv       = (const float*)d_in[4];
  const float* bv       = (const float*)d_in[5];
  const float* Wq       = (const float*)d_in[6];
  const float* bq       = (const float*)d_in[7];
  const float* Wl       = (const float*)d_in[8];
  // d_in[9] = bl (softmax-invariant, and zero)
  float* out = (float*)d_out;

  char* ws = (char*)d_ws;
  float*          vpw = (float*)(ws);                         // 800*512*4   = 1,638,400
  float*          qpw = (float*)(ws + 1638400);               // 4096*512*4  = 8,388,608
  unsigned short* vb  = (unsigned short*)(ws + 10027008);     // 800*1024*2  = 1,638,400
  unsigned short* wvb = (unsigned short*)(ws + 11665408);     // 512*1024*2  = 1,048,576
  unsigned short* qb  = (unsigned short*)(ws + 12713984);     // 4096*768*2  = 6,291,456
  unsigned short* wqb = (unsigned short*)(ws + 19005440);     // 512*768*2   =   786,432
                                                              // total ~19.8 MB

  cvt_all<<<2048, 256, 0, stream>>>(v, Wv, q, Wq, vb, wvb, qb, wqb);
  gemm_bt<<<dim3(8, 7),  256, 0, stream>>>(vb, wvb, bv, vpw,  800, 1024, 512);
  gemm_bt<<<dim3(8, 32), 256, 0, stream>>>(qb, wqb, bq, qpw, 4096,  768, 512);
  stage3_kernel<<<dim3(16, 16), 256, 0, stream>>>(vpw, qpw, Wl, box_mask, out);
}

// Round 2
// 89.059 us; speedup vs baseline: 1.4206x; 1.4206x over previous
//
#include <hip/hip_runtime.h>
#include <hip/hip_bf16.h>
#include <cstddef>

// ---------------------------------------------------------------------------
// Problem dims: B=16, N=4, S=64, K=50, VD=1024, QD=768, H=512
//   v_proj[b,k,h]   = v[b,0,k,:]   . Wv[h,:] + bv[h]     (M1=800,  K=1024, N=512)
//   q_proj[b,n,s,h] = q[b,n,s,0,:] . Wq[h,:] + bq[h]     (M2=4096, K=768,  N=512)
//   logits[row,k]   = sum_h Wl[h] * tanh(vp[k,h] + qp[row,h])
//                   = const - 2*sum_h Wl[h] * rcp(exp2(CEXP*(vp+qp)) + 1)
//     (const is k-uniform -> softmax-invariant -> dropped; CEXP=2*log2(e)
//      is baked into the GEMM epilogues so the inner loop has no mul)
//   out = masked softmax over k (50 boxes)
// ---------------------------------------------------------------------------

typedef __attribute__((ext_vector_type(4))) float  f32x4;
typedef __attribute__((ext_vector_type(8))) short  bfrag;   // 8 bf16 = 4 VGPRs
typedef __attribute__((ext_vector_type(4))) unsigned short u16x4;

__device__ __forceinline__ void gload16(const void* g, void* l) {
  __builtin_amdgcn_global_load_lds((const __attribute__((address_space(1))) void*)g,
                                   (__attribute__((address_space(3))) void*)l, 16, 0, 0);
}

__device__ __forceinline__ unsigned short f2bf(float f) {
  unsigned int u = __float_as_uint(f);
  u = (u + 0x7FFFu + ((u >> 16) & 1u)) >> 16;   // RTN-even; inputs finite
  return (unsigned short)u;
}

// ---------------------------------------------------------------------------
// fp32 -> bf16 conversion of v, Wv, q, Wq (single fused kernel, float4 granularity)
// segments (in float4 units): v 204800 | Wv 131072 | q 786432 | Wq 98304
// ---------------------------------------------------------------------------
__global__ void __launch_bounds__(256) cvt_all(
    const float* __restrict__ v, const float* __restrict__ wv,
    const float* __restrict__ q, const float* __restrict__ wq,
    unsigned short* __restrict__ vb, unsigned short* __restrict__ wvb,
    unsigned short* __restrict__ qb, unsigned short* __restrict__ wqb) {
  const int total = 1220608;
  for (int f = blockIdx.x * 256 + threadIdx.x; f < total; f += gridDim.x * 256) {
    const float* src; unsigned short* dst; int off;
    if (f < 204800)       { src = v;  dst = vb;  off = f; }
    else if (f < 335872)  { src = wv; dst = wvb; off = f - 204800; }
    else if (f < 1122304) { src = q;  dst = qb;  off = f - 335872; }
    else                  { src = wq; dst = wqb; off = f - 1122304; }
    f32x4 x = ((const f32x4*)src)[off];
    u16x4 o;
    o[0] = f2bf(x[0]); o[1] = f2bf(x[1]); o[2] = f2bf(x[2]); o[3] = f2bf(x[3]);
    ((u16x4*)dst)[off] = o;
  }
}

// ---------------------------------------------------------------------------
// bf16 GEMM: C[M,N] = (A[M,Kd] * W[N,Kd]^T + bias[N]) * scale, fp32 out.
// Tile 128(M) x 64(N), BK=32. 256 threads = 4 waves (2x2), wave tile 64x32.
// ---------------------------------------------------------------------------
__global__ void __launch_bounds__(256) gemm_bt(
    const unsigned short* __restrict__ A, const unsigned short* __restrict__ W,
    const float* __restrict__ bias, float* __restrict__ C,
    int M, int Kd, int Nd, float scale) {
  __shared__ unsigned short As[128 * 32];   // [row][k] linear
  __shared__ unsigned short Bs[64 * 32];

  const int t    = threadIdx.x;
  const int lane = t & 63;
  const int wave = t >> 6;
  const int wm   = wave >> 1;      // 0..1
  const int wn   = wave & 1;       // 0..1
  const int la   = lane & 15;      // frag row/col
  const int lb   = lane >> 4;      // k-group (0..3)
  const int m0   = blockIdx.y * 128;
  const int n0   = blockIdx.x * 64;

  f32x4 acc[4][2] = {};

  for (int k0 = 0; k0 < Kd; k0 += 32) {
    __syncthreads();
#pragma unroll
    for (int i = 0; i < 2; ++i) {
      int c   = i * 256 + t;
      int row = c >> 2;
      int kk  = (c & 3) * 8;
      int gr  = m0 + row; if (gr >= M) gr = M - 1;   // clamp (store-side guarded)
      gload16(A + (size_t)gr * Kd + k0 + kk, (char*)As + c * 16);
    }
    {
      int row = t >> 2;
      int kk  = (t & 3) * 8;
      gload16(W + (size_t)(n0 + row) * Kd + k0 + kk, (char*)Bs + t * 16);
    }
    __syncthreads();

    bfrag a[4], b[2];
#pragma unroll
    for (int r = 0; r < 4; ++r)
      a[r] = *(const bfrag*)&As[(wm * 64 + r * 16 + la) * 32 + lb * 8];
#pragma unroll
    for (int c = 0; c < 2; ++c)
      b[c] = *(const bfrag*)&Bs[(wn * 32 + c * 16 + la) * 32 + lb * 8];
#pragma unroll
    for (int r = 0; r < 4; ++r)
#pragma unroll
      for (int c = 0; c < 2; ++c)
        acc[r][c] = __builtin_amdgcn_mfma_f32_16x16x32_bf16(a[r], b[c], acc[r][c], 0, 0, 0);
  }

  // epilogue: D lane layout col = lane&15, row = (lane>>4)*4 + reg
#pragma unroll
  for (int c = 0; c < 2; ++c) {
    int col = n0 + wn * 32 + c * 16 + la;
    float bcol = bias[col];
#pragma unroll
    for (int r = 0; r < 4; ++r) {
      int mbase = m0 + wm * 64 + r * 16 + lb * 4;
#pragma unroll
      for (int e = 0; e < 4; ++e) {
        int mr = mbase + e;
        if (mr < M) C[(size_t)mr * Nd + col] = (acc[r][c][e] + bcol) * scale;
      }
    }
  }
}

// ---------------------------------------------------------------------------
// Stage 3: logits + masked softmax, fused.
// grid (64 row-chunks, 16 b), 256 threads = 4 waves. Wave = one output row,
// lane = one box k (50 active of 64). h streamed in LDS chunks of 64.
// vp/qp arrive pre-scaled by 2*log2(e); w2 = -2*wl staged in LDS.
// Softmax = wave-level shuffle reduction (no serial loop, no LDS logits).
// ---------------------------------------------------------------------------
__global__ void __launch_bounds__(256) stage3_kernel(
    const float* __restrict__ vp, const float* __restrict__ qp,
    const float* __restrict__ wl, const int* __restrict__ box_mask,
    float* __restrict__ out) {
  __shared__ float vpS[50][68];
  __shared__ float qpS[4][68];
  __shared__ float w2S[68];

  const int b     = blockIdx.y;
  const int chunk = blockIdx.x;          // 0..63
  const int t     = threadIdx.x;
  const int wv    = t >> 6;              // row within block, 0..3
  const int k     = t & 63;              // box id (lane)
  const int row   = chunk * 4 + wv;      // 0..255
  const int kc    = (k < 50) ? k : 0;    // clamped LDS row (idle lanes read row 0)

  float acc = 0.f;

  for (int h0 = 0; h0 < 512; h0 += 64) {
    __syncthreads();
    // stage vp chunk: 50 * 16 = 800 float4s
    for (int f = t; f < 800; f += 256) {
      int kk = f >> 4, hh = (f & 15) << 2;
      *(f32x4*)&vpS[kk][hh] = *(const f32x4*)&vp[(size_t)(b * 50 + kk) * 512 + h0 + hh];
    }
    // stage qp: 4 rows x 16 float4s
    if (t < 64) {
      int r = t >> 4, hh = (t & 15) << 2;
      *(f32x4*)&qpS[r][hh] = *(const f32x4*)&qp[(size_t)(b * 256 + chunk * 4 + r) * 512 + h0 + hh];
    } else if (t < 80) {
      int i = t - 64;
      f32x4 w = *(const f32x4*)&wl[h0 + i * 4];
      *(f32x4*)&w2S[i * 4] = w * -2.0f;
    }
    __syncthreads();

    for (int hh = 0; hh < 64; hh += 4) {
      f32x4 q4 = *(const f32x4*)&qpS[wv][hh];     // wave-uniform broadcast
      f32x4 w4 = *(const f32x4*)&w2S[hh];         // broadcast
      f32x4 v4 = *(const f32x4*)&vpS[kc][hh];
#pragma unroll
      for (int e = 0; e < 4; ++e) {
        float x  = v4[e] + q4[e];                          // pre-scaled by 2*log2e
        float ex = __builtin_amdgcn_exp2f(x);
        float rc = __builtin_amdgcn_rcpf(ex + 1.0f);
        acc = fmaf(w4[e], rc, acc);                        // w4 = -2*wl
      }
    }
  }

  // masked softmax over lanes 0..49 within this wave
  int   msk = (k < 50) ? box_mask[b * 50 + k] : 0;
  float l   = (k < 50 && msk > 0) ? acc : -1e9f;

  float mx = l;
#pragma unroll
  for (int off = 32; off; off >>= 1) mx = fmaxf(mx, __shfl_xor(mx, off));
  float e = (k < 50) ? __builtin_amdgcn_exp2f((l - mx) * 1.4426950408889634f) : 0.f;
  float s = e;
#pragma unroll
  for (int off = 32; off; off >>= 1) s += __shfl_xor(s, off);

  if (k < 50) out[(size_t)(b * 256 + row) * 50 + k] = e / s;
}

// ---------------------------------------------------------------------------
// launch
// ---------------------------------------------------------------------------
extern "C" void kernel_launch(void* const* d_in, const int* in_sizes, int n_in,
                              void* d_out, int out_size, void* d_ws, size_t ws_size,
                              hipStream_t stream) {
  const float* v        = (const float*)d_in[0];
  const float* q        = (const float*)d_in[1];
  const int*   box_mask = (const int*)d_in[2];
  // d_in[3] = tags_attention (unused by reference)
  const float* Wv       = (const float*)d_in[4];
  const float* bv       = (const float*)d_in[5];
  const float* Wq       = (const float*)d_in[6];
  const float* bq       = (const float*)d_in[7];
  const float* Wl       = (const float*)d_in[8];
  // d_in[9] = bl (softmax-invariant, and zero)
  float* out = (float*)d_out;

  char* ws = (char*)d_ws;
  float*          vpw = (float*)(ws);                         // 800*512*4   = 1,638,400
  float*          qpw = (float*)(ws + 1638400);               // 4096*512*4  = 8,388,608
  unsigned short* vb  = (unsigned short*)(ws + 10027008);     // 800*1024*2  = 1,638,400
  unsigned short* wvb = (unsigned short*)(ws + 11665408);     // 512*1024*2  = 1,048,576
  unsigned short* qb  = (unsigned short*)(ws + 12713984);     // 4096*768*2  = 6,291,456
  unsigned short* wqb = (unsigned short*)(ws + 19005440);     // 512*768*2   =   786,432
                                                              // total ~19.8 MB

  const float CEXP = 2.885390081777927f;   // 2*log2(e), folded into both GEMMs

  cvt_all<<<2048, 256, 0, stream>>>(v, Wv, q, Wq, vb, wvb, qb, wqb);
  gemm_bt<<<dim3(8, 7),  256, 0, stream>>>(vb, wvb, bv, vpw,  800, 1024, 512, CEXP);
  gemm_bt<<<dim3(8, 32), 256, 0, stream>>>(qb, wqb, bq, qpw, 4096,  768, 512, CEXP);
  stage3_kernel<<<dim3(64, 16), 256, 0, stream>>>(vpw, qpw, Wl, box_mask, out);
}

// Round 3
// 75.194 us; speedup vs baseline: 1.6826x; 1.1844x over previous
//
#include <hip/hip_runtime.h>
#include <hip/hip_bf16.h>
#include <cstddef>

// ---------------------------------------------------------------------------
// B=16, N=4, S=64, K=50, VD=1024, QD=768, H=512; ROWS = B*N*S = 4096
//   vp_T[h][k_glob] = CEXP*(v[b,k,:]  .Wv[h,:] + bv[h])   (transposed output!)
//   qp[row][h]      = CEXP*(q[row,:]  .Wq[h,:] + bq[h])
//   logit[row][k]   = -2 * sum_h wl[h] * rcp(exp2(vp_T[h][k] + qp[row][h]) + 1)
//     (tanh identity; k-uniform const dropped — softmax-invariant; CEXP=2*log2e
//      folded into both GEMM epilogues)
//   out = masked softmax over k (50 boxes)
// ---------------------------------------------------------------------------

typedef __attribute__((ext_vector_type(4))) float        f32x4;
typedef __attribute__((ext_vector_type(8))) short        bfrag;   // 8 bf16
typedef __attribute__((ext_vector_type(2))) unsigned int u32x2;

#define LDC_VT 832   // vp_T leading dim (800 rows padded; 15*50+63=813 < 832)

__device__ __forceinline__ void gload4(const float* g, float* l) {
  __builtin_amdgcn_global_load_lds((const __attribute__((address_space(1))) void*)g,
                                   (__attribute__((address_space(3))) void*)l, 4, 0, 0);
}

__device__ __forceinline__ unsigned int cvtpk(float a, float b) {
  unsigned int r;
  asm("v_cvt_pk_bf16_f32 %0, %1, %2" : "=v"(r) : "v"(a), "v"(b));
  return r;   // low16 = bf16(a), high16 = bf16(b)
}

// ---------------------------------------------------------------------------
// Fused GEMM: one dispatch does both projections (bf16 MFMA, fp32 in/out).
//   grid.y in [0,7)   : v-proj  M=800,  Kd=1024, C = vp_T (transposed, ldc=832)
//   grid.y in [7,39)  : q-proj  M=4096, Kd=768,  C = qp   (row-major,  ldc=512)
// Tile 128(M) x 64(N), BK=32, 4 waves. fp32->bf16 conversion fused into staging
// (reg-staged: global f32x4 -> v_cvt_pk_bf16_f32 -> ds_write_b64).
// ---------------------------------------------------------------------------
__global__ void __launch_bounds__(256) gemm_fused(
    const float* __restrict__ v,  const float* __restrict__ q,
    const float* __restrict__ Wv, const float* __restrict__ bv,
    const float* __restrict__ Wq, const float* __restrict__ bq,
    float* __restrict__ vpT, float* __restrict__ qp) {
  __shared__ unsigned short As[128 * 32];
  __shared__ unsigned short Bs[64 * 32];

  const int t  = threadIdx.x;
  const int by = blockIdx.y;

  const float* A; const float* W; const float* bias; float* C;
  int M, Kd, ldc, m0, transC;
  if (by < 7) { A = v; W = Wv; bias = bv; C = vpT; M = 800;  Kd = 1024; ldc = LDC_VT; m0 = by * 128;       transC = 1; }
  else        { A = q; W = Wq; bias = bq; C = qp;  M = 4096; Kd = 768;  ldc = 512;    m0 = (by - 7) * 128; transC = 0; }
  const int n0 = blockIdx.x * 64;

  const int lane = t & 63;
  const int wave = t >> 6;
  const int wm   = wave >> 1;
  const int wn   = wave & 1;
  const int la   = lane & 15;
  const int lb   = lane >> 4;

  f32x4 acc[4][2] = {};

  for (int k0 = 0; k0 < Kd; k0 += 32) {
    __syncthreads();
    // A tile: 128 rows x 32 k fp32 -> bf16. 1024 f32x4 chunks, 4 per thread.
#pragma unroll
    for (int i = 0; i < 4; ++i) {
      int f = i * 256 + t;
      int row = f >> 3, k4 = f & 7;
      int gr = m0 + row; if (gr >= M) gr = M - 1;          // clamp; store-side guarded
      f32x4 x = *(const f32x4*)&A[(size_t)gr * Kd + k0 + k4 * 4];
      u32x2 p; p[0] = cvtpk(x[0], x[1]); p[1] = cvtpk(x[2], x[3]);
      *(u32x2*)&As[row * 32 + k4 * 4] = p;
    }
    // B tile: 64 rows x 32 k. 512 chunks, 2 per thread.
#pragma unroll
    for (int i = 0; i < 2; ++i) {
      int f = i * 256 + t;
      int row = f >> 3, k4 = f & 7;
      f32x4 x = *(const f32x4*)&W[(size_t)(n0 + row) * Kd + k0 + k4 * 4];
      u32x2 p; p[0] = cvtpk(x[0], x[1]); p[1] = cvtpk(x[2], x[3]);
      *(u32x2*)&Bs[row * 32 + k4 * 4] = p;
    }
    __syncthreads();

    bfrag a[4], b[2];
#pragma unroll
    for (int r = 0; r < 4; ++r)
      a[r] = *(const bfrag*)&As[(wm * 64 + r * 16 + la) * 32 + lb * 8];
#pragma unroll
    for (int c = 0; c < 2; ++c)
      b[c] = *(const bfrag*)&Bs[(wn * 32 + c * 16 + la) * 32 + lb * 8];
#pragma unroll
    for (int r = 0; r < 4; ++r)
#pragma unroll
      for (int c = 0; c < 2; ++c)
        acc[r][c] = __builtin_amdgcn_mfma_f32_16x16x32_bf16(a[r], b[c], acc[r][c], 0, 0, 0);
  }

  const float CEXP = 2.885390081777927f;   // 2*log2(e)
#pragma unroll
  for (int c = 0; c < 2; ++c) {
    int col = n0 + wn * 32 + c * 16 + la;
    float bcol = bias[col];
#pragma unroll
    for (int r = 0; r < 4; ++r) {
      int mbase = m0 + wm * 64 + r * 16 + lb * 4;
#pragma unroll
      for (int e = 0; e < 4; ++e) {
        int mr = mbase + e;
        if (mr < M) {
          size_t idx = transC ? (size_t)col * ldc + mr : (size_t)mr * ldc + col;
          C[idx] = (acc[r][c][e] + bcol) * CEXP;
        }
      }
    }
  }
}

// ---------------------------------------------------------------------------
// Stage 3: logits + masked softmax.
// grid (64 chunks, 16 b), 256 thr = 4 waves; wave = one row, lane = box k.
// vp_T staged via global_load_lds into vpS[h][64] (stride 64 -> 2-way = free).
// h chunked by 128 (4 chunks, 8 barriers). qp/wl also global_load_lds.
// ---------------------------------------------------------------------------
__global__ void __launch_bounds__(256) stage3_kernel(
    const float* __restrict__ vpT, const float* __restrict__ qp,
    const float* __restrict__ wl,  const int* __restrict__ box_mask,
    float* __restrict__ out) {
  __shared__ float vpS[128][64];   // 32 KB
  __shared__ float qpS[4][128];    // 2 KB
  __shared__ float wlS[128];       // 0.5 KB

  const int b     = blockIdx.y;
  const int chunk = blockIdx.x;            // 0..63
  const int t     = threadIdx.x;
  const int wv    = t >> 6;                // wave = row-in-block
  const int k     = t & 63;                // box id
  const int rowg  = b * 256 + chunk * 4 + wv;

  float a0 = 0.f, a1 = 0.f, a2 = 0.f, a3 = 0.f;

  for (int h0 = 0; h0 < 512; h0 += 128) {
    __syncthreads();
    // vp: wave wv stages h-rows [wv*32, wv*32+32)
#pragma unroll
    for (int i = 0; i < 32; ++i) {
      int hh = wv * 32 + i;
      gload4(vpT + (size_t)(h0 + hh) * LDC_VT + b * 50 + k, &vpS[hh][0]);
    }
    // qp: each wave stages its own row (128 h = 2 loads)
    {
      const float* qrow = qp + (size_t)rowg * 512 + h0;
      gload4(qrow + k,      &qpS[wv][0]);
      gload4(qrow + 64 + k, &qpS[wv][64]);
    }
    if (wv == 0) {
      gload4(wl + h0 + k,      &wlS[0]);
      gload4(wl + h0 + 64 + k, &wlS[64]);
    }
    __syncthreads();

#pragma unroll 8
    for (int hh = 0; hh < 128; hh += 4) {
      f32x4 q4 = *(const f32x4*)&qpS[wv][hh];   // wave-uniform broadcast
      f32x4 w4 = *(const f32x4*)&wlS[hh];       // broadcast
      float v0 = vpS[hh + 0][k];
      float v1 = vpS[hh + 1][k];
      float v2 = vpS[hh + 2][k];
      float v3 = vpS[hh + 3][k];
      a0 = fmaf(w4[0], __builtin_amdgcn_rcpf(__builtin_amdgcn_exp2f(v0 + q4[0]) + 1.f), a0);
      a1 = fmaf(w4[1], __builtin_amdgcn_rcpf(__builtin_amdgcn_exp2f(v1 + q4[1]) + 1.f), a1);
      a2 = fmaf(w4[2], __builtin_amdgcn_rcpf(__builtin_amdgcn_exp2f(v2 + q4[2]) + 1.f), a2);
      a3 = fmaf(w4[3], __builtin_amdgcn_rcpf(__builtin_amdgcn_exp2f(v3 + q4[3]) + 1.f), a3);
    }
  }

  float logit = -2.f * ((a0 + a1) + (a2 + a3));

  // masked softmax over lanes 0..49
  int   msk = (k < 50) ? box_mask[b * 50 + k] : 0;
  float l   = (k < 50 && msk > 0) ? logit : -1e9f;

  float mx = l;
#pragma unroll
  for (int off = 32; off; off >>= 1) mx = fmaxf(mx, __shfl_xor(mx, off));
  float e = (k < 50) ? __builtin_amdgcn_exp2f((l - mx) * 1.4426950408889634f) : 0.f;
  float s = e;
#pragma unroll
  for (int off = 32; off; off >>= 1) s += __shfl_xor(s, off);

  if (k < 50) out[(size_t)rowg * 50 + k] = e / s;
}

// ---------------------------------------------------------------------------
// launch
// ---------------------------------------------------------------------------
extern "C" void kernel_launch(void* const* d_in, const int* in_sizes, int n_in,
                              void* d_out, int out_size, void* d_ws, size_t ws_size,
                              hipStream_t stream) {
  const float* v        = (const float*)d_in[0];
  const float* q        = (const float*)d_in[1];
  const int*   box_mask = (const int*)d_in[2];
  // d_in[3] = tags_attention (unused by reference)
  const float* Wv       = (const float*)d_in[4];
  const float* bv       = (const float*)d_in[5];
  const float* Wq       = (const float*)d_in[6];
  const float* bq       = (const float*)d_in[7];
  const float* Wl       = (const float*)d_in[8];
  // d_in[9] = bl (softmax-invariant, and zero)
  float* out = (float*)d_out;

  char* ws = (char*)d_ws;
  float* vpT = (float*)(ws);             // 512*832*4  = 1,703,936 B
  float* qp  = (float*)(ws + 1703936);   // 4096*512*4 = 8,388,608 B  (total ~10.1 MB)

  gemm_fused<<<dim3(8, 39), 256, 0, stream>>>(v, q, Wv, bv, Wq, bq, vpT, qp);
  stage3_kernel<<<dim3(64, 16), 256, 0, stream>>>(vpT, qp, Wl, box_mask, out);
}

// Round 4
// 66.045 us; speedup vs baseline: 1.9157x; 1.1385x over previous
//
#include <hip/hip_runtime.h>
#include <hip/hip_bf16.h>
#include <cstddef>

// ---------------------------------------------------------------------------
// B=16, N=4, S=64, K=50, VD=1024, QD=768, H=512; ROWS = B*N*S = 4096
//   vp_T[h][k_glob] = CEXP*(v[b,k,:] .Wv[h,:] + bv[h])   (transposed output)
//   qp[row][h]      = CEXP*(q[row,:] .Wq[h,:] + bq[h])
//   logit[row][k]   = -2 * sum_h wl[h] * rcp(exp2(vp_T[h][k] + qp[row][h]) + 1)
//     (tanh identity; k-uniform const dropped; CEXP=2*log2e folded into GEMMs)
//   out = masked softmax over k (50 boxes)
// ---------------------------------------------------------------------------

typedef __attribute__((ext_vector_type(4))) float        f32x4;
typedef __attribute__((ext_vector_type(8))) short        bfrag;   // 8 bf16
typedef __attribute__((ext_vector_type(4))) unsigned int u32x4;

#define LDC_VT 832   // vp_T leading dim (15*50+63=813 < 832)

__device__ __forceinline__ void gload4(const float* g, float* l) {
  __builtin_amdgcn_global_load_lds((const __attribute__((address_space(1))) void*)g,
                                   (__attribute__((address_space(3))) void*)l, 4, 0, 0);
}

__device__ __forceinline__ unsigned int cvtpk(float a, float b) {
  unsigned int r;
  asm("v_cvt_pk_bf16_f32 %0, %1, %2" : "=v"(r) : "v"(a), "v"(b));
  return r;   // low16 = bf16(a), high16 = bf16(b)
}

// ---------------------------------------------------------------------------
// Fused GEMM, software-pipelined (2-deep reg lookahead + LDS double buffer).
//   grid.y in [0,13)  : v-proj  M=800,  Kd=1024, C = vp_T (transposed, ldc=832)
//   grid.y in [13,77) : q-proj  M=4096, Kd=768,  C = qp   (row-major,  ldc=512)
// Tile 64(M) x 64(N), BK=64, 4 waves (2x2), wave tile 32x32.
// fp32->bf16 fused into staging (v_cvt_pk_bf16_f32). LDS XOR-swizzled:
// byte ^= (row&7)<<4  -> ds_write_b128 conflict-free, frag reads 2-way (free).
// ---------------------------------------------------------------------------
__global__ void __launch_bounds__(256) gemm_fused(
    const float* __restrict__ v,  const float* __restrict__ q,
    const float* __restrict__ Wv, const float* __restrict__ bv,
    const float* __restrict__ Wq, const float* __restrict__ bq,
    float* __restrict__ vpT, float* __restrict__ qp) {
  __shared__ unsigned short As[2][64 * 64];   // 8 KB per buf
  __shared__ unsigned short Bs[2][64 * 64];

  const int t  = threadIdx.x;
  const int by = blockIdx.y;

  const float* A; const float* W; const float* bias; float* C;
  int M, Kd, ldc, m0, transC;
  if (by < 13) { A = v; W = Wv; bias = bv; C = vpT; M = 800;  Kd = 1024; ldc = LDC_VT; m0 = by * 64;        transC = 1; }
  else         { A = q; W = Wq; bias = bq; C = qp;  M = 4096; Kd = 768;  ldc = 512;    m0 = (by - 13) * 64; transC = 0; }
  const int n0 = blockIdx.x * 64;

  const int lane = t & 63;
  const int wave = t >> 6;
  const int wm   = wave >> 1;
  const int wn   = wave & 1;
  const int la   = lane & 15;
  const int lb   = lane >> 4;

  // staging assignment: thread -> (row srow, 16-wide k slice at skq)
  const int srow = t >> 2;
  const int skq  = (t & 3) * 16;

  int gr = m0 + srow; if (gr >= M) gr = M - 1;     // clamp; store-side guarded
  const float* Arow = A + (size_t)gr * Kd + skq;
  const float* Wrow = W + (size_t)(n0 + srow) * Kd + skq;

  f32x4 acc[2][2] = {};
  f32x4 raA[4], rbA[4], raB[4], rbB[4];

  auto loadG = [&](f32x4* ra, f32x4* rb, int s) {
    const float* ap = Arow + s * 64;
    const float* wp = Wrow + s * 64;
#pragma unroll
    for (int i = 0; i < 4; ++i) ra[i] = *(const f32x4*)&ap[i * 4];
#pragma unroll
    for (int i = 0; i < 4; ++i) rb[i] = *(const f32x4*)&wp[i * 4];
  };

  const int o0 = (srow * 128 + skq * 2)      ^ ((srow & 7) << 4);
  const int o1 = (srow * 128 + skq * 2 + 16) ^ ((srow & 7) << 4);

  auto writeL = [&](unsigned short* da, unsigned short* db,
                    const f32x4* ra, const f32x4* rb) {
    u32x4 p;
    p[0] = cvtpk(ra[0][0], ra[0][1]); p[1] = cvtpk(ra[0][2], ra[0][3]);
    p[2] = cvtpk(ra[1][0], ra[1][1]); p[3] = cvtpk(ra[1][2], ra[1][3]);
    *(u32x4*)((char*)da + o0) = p;
    p[0] = cvtpk(ra[2][0], ra[2][1]); p[1] = cvtpk(ra[2][2], ra[2][3]);
    p[2] = cvtpk(ra[3][0], ra[3][1]); p[3] = cvtpk(ra[3][2], ra[3][3]);
    *(u32x4*)((char*)da + o1) = p;
    p[0] = cvtpk(rb[0][0], rb[0][1]); p[1] = cvtpk(rb[0][2], rb[0][3]);
    p[2] = cvtpk(rb[1][0], rb[1][1]); p[3] = cvtpk(rb[1][2], rb[1][3]);
    *(u32x4*)((char*)db + o0) = p;
    p[0] = cvtpk(rb[2][0], rb[2][1]); p[1] = cvtpk(rb[2][2], rb[2][3]);
    p[2] = cvtpk(rb[3][0], rb[3][1]); p[3] = cvtpk(rb[3][2], rb[3][3]);
    *(u32x4*)((char*)db + o1) = p;
  };

  auto compute = [&](const unsigned short* sa, const unsigned short* sb) {
    bfrag af[2][2], bf[2][2];
#pragma unroll
    for (int r = 0; r < 2; ++r)
#pragma unroll
      for (int kk = 0; kk < 2; ++kk) {
        int rowa = wm * 32 + r * 16 + la;
        af[r][kk] = *(const bfrag*)((const char*)sa +
                     ((rowa * 128 + kk * 64 + lb * 16) ^ ((rowa & 7) << 4)));
        int rowb = wn * 32 + r * 16 + la;
        bf[r][kk] = *(const bfrag*)((const char*)sb +
                     ((rowb * 128 + kk * 64 + lb * 16) ^ ((rowb & 7) << 4)));
      }
#pragma unroll
    for (int kk = 0; kk < 2; ++kk)
#pragma unroll
      for (int r = 0; r < 2; ++r)
#pragma unroll
        for (int c = 0; c < 2; ++c)
          acc[r][c] = __builtin_amdgcn_mfma_f32_16x16x32_bf16(af[r][kk], bf[c][kk], acc[r][c], 0, 0, 0);
  };

  // pipeline: nsteps is even for both paths (16 / 12)
  const int nsteps = Kd >> 6;
  loadG(raA, rbA, 0);
  writeL(As[0], Bs[0], raA, rbA);
  loadG(raB, rbB, 1);
  __syncthreads();
  for (int s = 0; s < nsteps; s += 2) {
    if (s + 2 < nsteps) loadG(raA, rbA, s + 2);
    compute(As[0], Bs[0]);
    writeL(As[1], Bs[1], raB, rbB);
    __syncthreads();
    if (s + 3 < nsteps) loadG(raB, rbB, s + 3);
    compute(As[1], Bs[1]);
    if (s + 2 < nsteps) writeL(As[0], Bs[0], raA, rbA);
    __syncthreads();
  }

  const float CEXP = 2.885390081777927f;   // 2*log2(e)
#pragma unroll
  for (int c = 0; c < 2; ++c) {
    int col = n0 + wn * 32 + c * 16 + la;
    float bcol = bias[col];
#pragma unroll
    for (int r = 0; r < 2; ++r) {
      int mbase = m0 + wm * 32 + r * 16 + lb * 4;
      if (transC) {
        if (mbase + 3 < M) {
          f32x4 o;
#pragma unroll
          for (int e = 0; e < 4; ++e) o[e] = (acc[r][c][e] + bcol) * CEXP;
          *(f32x4*)&C[(size_t)col * ldc + mbase] = o;
        } else {
#pragma unroll
          for (int e = 0; e < 4; ++e)
            if (mbase + e < M) C[(size_t)col * ldc + mbase + e] = (acc[r][c][e] + bcol) * CEXP;
        }
      } else {
#pragma unroll
        for (int e = 0; e < 4; ++e)
          C[(size_t)(mbase + e) * ldc + col] = (acc[r][c][e] + bcol) * CEXP;
      }
    }
  }
}

// ---------------------------------------------------------------------------
// Stage 3: logits + masked softmax. grid (32 chunks, 16 b), 512 thr = 8 waves.
// Wave = one row, lane = box k. vp_T staged via global_load_lds into
// vpS[h][64] (stride 64 -> 2-way = free). 64-h chunks, double-buffered:
// chunk c+1's loads issued before computing chunk c; one barrier per chunk.
// ---------------------------------------------------------------------------
__global__ void __launch_bounds__(512) stage3_kernel(
    const float* __restrict__ vpT, const float* __restrict__ qp,
    const float* __restrict__ wl,  const int* __restrict__ box_mask,
    float* __restrict__ out) {
  __shared__ float vpS[2][64][64];   // 32 KB
  __shared__ float qpS[2][8][64];    //  4 KB
  __shared__ float wlS[2][64];       // .5 KB

  const int b     = blockIdx.y;
  const int chunk = blockIdx.x;            // 0..31
  const int t     = threadIdx.x;
  const int wv    = t >> 6;                // 0..7: wave = row-in-block
  const int k     = t & 63;                // box id
  const int rowg  = b * 256 + chunk * 8 + wv;
  const float* qrow = qp + (size_t)rowg * 512;

  auto STAGE = [&](int buf, int h0) {
#pragma unroll
    for (int i = 0; i < 8; ++i) {
      int hh = wv * 8 + i;
      gload4(vpT + (size_t)(h0 + hh) * LDC_VT + b * 50 + k, &vpS[buf][hh][0]);
    }
    gload4(qrow + h0 + k, &qpS[buf][wv][0]);
    if (wv == 0) gload4(wl + h0 + k, &wlS[buf][0]);
  };

  float a0 = 0.f, a1 = 0.f, a2 = 0.f, a3 = 0.f;

  STAGE(0, 0);
  __syncthreads();
  int buf = 0;
  for (int c = 0; c < 8; ++c) {
    if (c < 7) STAGE(buf ^ 1, (c + 1) * 64);
#pragma unroll 4
    for (int hh = 0; hh < 64; hh += 4) {
      f32x4 q4 = *(const f32x4*)&qpS[buf][wv][hh];   // wave-uniform broadcast
      f32x4 w4 = *(const f32x4*)&wlS[buf][hh];       // broadcast
      float v0 = vpS[buf][hh + 0][k];
      float v1 = vpS[buf][hh + 1][k];
      float v2 = vpS[buf][hh + 2][k];
      float v3 = vpS[buf][hh + 3][k];
      a0 = fmaf(w4[0], __builtin_amdgcn_rcpf(__builtin_amdgcn_exp2f(v0 + q4[0]) + 1.f), a0);
      a1 = fmaf(w4[1], __builtin_amdgcn_rcpf(__builtin_amdgcn_exp2f(v1 + q4[1]) + 1.f), a1);
      a2 = fmaf(w4[2], __builtin_amdgcn_rcpf(__builtin_amdgcn_exp2f(v2 + q4[2]) + 1.f), a2);
      a3 = fmaf(w4[3], __builtin_amdgcn_rcpf(__builtin_amdgcn_exp2f(v3 + q4[3]) + 1.f), a3);
    }
    __syncthreads();   // drains vmcnt(0): chunk c+1 staged, buf^1 safe to reuse
    buf ^= 1;
  }

  float logit = -2.f * ((a0 + a1) + (a2 + a3));

  // masked softmax over lanes 0..49
  int   msk = (k < 50) ? box_mask[b * 50 + k] : 0;
  float l   = (k < 50 && msk > 0) ? logit : -1e9f;

  float mx = l;
#pragma unroll
  for (int off = 32; off; off >>= 1) mx = fmaxf(mx, __shfl_xor(mx, off));
  float e = (k < 50) ? __builtin_amdgcn_exp2f((l - mx) * 1.4426950408889634f) : 0.f;
  float s = e;
#pragma unroll
  for (int off = 32; off; off >>= 1) s += __shfl_xor(s, off);

  if (k < 50) out[(size_t)rowg * 50 + k] = e / s;
}

// ---------------------------------------------------------------------------
// launch
// ---------------------------------------------------------------------------
extern "C" void kernel_launch(void* const* d_in, const int* in_sizes, int n_in,
                              void* d_out, int out_size, void* d_ws, size_t ws_size,
                              hipStream_t stream) {
  const float* v        = (const float*)d_in[0];
  const float* q        = (const float*)d_in[1];
  const int*   box_mask = (const int*)d_in[2];
  // d_in[3] = tags_attention (unused by reference)
  const float* Wv       = (const float*)d_in[4];
  const float* bv       = (const float*)d_in[5];
  const float* Wq       = (const float*)d_in[6];
  const float* bq       = (const float*)d_in[7];
  const float* Wl       = (const float*)d_in[8];
  // d_in[9] = bl (softmax-invariant, and zero)
  float* out = (float*)d_out;

  char* ws = (char*)d_ws;
  float* vpT = (float*)(ws);             // 512*832*4  = 1,703,936 B
  float* qp  = (float*)(ws + 1703936);   // 4096*512*4 = 8,388,608 B

  gemm_fused<<<dim3(8, 77),  256, 0, stream>>>(v, q, Wv, bv, Wq, bq, vpT, qp);
  stage3_kernel<<<dim3(32, 16), 512, 0, stream>>>(vpT, qp, Wl, box_mask, out);
}

// Round 5
// 56.556 us; speedup vs baseline: 2.2371x; 1.1678x over previous
//
#include <hip/hip_runtime.h>
#include <hip/hip_bf16.h>
#include <cstddef>

// ---------------------------------------------------------------------------
// B=16, N=4, S=64, K=50, VD=1024, QD=768, H=512; ROWS = B*N*S = 4096
//   Ev_T[h][k_glob] = exp2(CEXP*(v[b,k,:] .Wv[h,:] + bv[h]))   (transposed)
//   Eq[row][h]      = exp2(CEXP*(q[row,:] .Wq[h,:] + bq[h]))
//   logit[row][k]   = -2 * sum_h wl[h] * rcp(Ev_T[h][k]*Eq[row][h] + 1)
//     (tanh(x) = 1 - 2/(e^{2x}+1); exp2 factorized out of the 105M-element
//      product space into the 4.9M-element projection spaces -> stage3 inner
//      is 2 VALU + 1 trans instead of 3 VALU + 2 trans. k-uniform sum_h wl
//      dropped: softmax-invariant. CEXP = 2*log2(e).)
//   out = masked softmax over k (50 boxes)
// ---------------------------------------------------------------------------

typedef __attribute__((ext_vector_type(4))) float        f32x4;
typedef __attribute__((ext_vector_type(8))) short        bfrag;   // 8 bf16
typedef __attribute__((ext_vector_type(4))) unsigned int u32x4;

#define LDC_VT 832   // Ev_T leading dim (15*50+63=813 < 832)

__device__ __forceinline__ void gload4(const float* g, float* l) {
  __builtin_amdgcn_global_load_lds((const __attribute__((address_space(1))) void*)g,
                                   (__attribute__((address_space(3))) void*)l, 4, 0, 0);
}

__device__ __forceinline__ unsigned int cvtpk(float a, float b) {
  unsigned int r;
  asm("v_cvt_pk_bf16_f32 %0, %1, %2" : "=v"(r) : "v"(a), "v"(b));
  return r;   // low16 = bf16(a), high16 = bf16(b)
}

// ---------------------------------------------------------------------------
// Fused GEMM, software-pipelined (2-deep reg lookahead + LDS double buffer).
//   grid.y in [0,13)  : v-proj  M=800,  Kd=1024, C = Ev_T (transposed, ldc=832)
//   grid.y in [13,77) : q-proj  M=4096, Kd=768,  C = Eq   (row-major,  ldc=512)
// Tile 64(M) x 64(N), BK=64, 4 waves (2x2), wave tile 32x32.
// fp32->bf16 fused into staging (v_cvt_pk_bf16_f32). LDS XOR-swizzled:
// byte ^= (row&7)<<4  -> ds_write_b128 conflict-free, frag reads 2-way (free).
// Epilogue stores exp2(CEXP*(acc+bias))  (the hoisted exp2 factor).
// ---------------------------------------------------------------------------
__global__ void __launch_bounds__(256) gemm_fused(
    const float* __restrict__ v,  const float* __restrict__ q,
    const float* __restrict__ Wv, const float* __restrict__ bv,
    const float* __restrict__ Wq, const float* __restrict__ bq,
    float* __restrict__ vpT, float* __restrict__ qp) {
  __shared__ unsigned short As[2][64 * 64];   // 8 KB per buf
  __shared__ unsigned short Bs[2][64 * 64];

  const int t  = threadIdx.x;
  const int by = blockIdx.y;

  const float* A; const float* W; const float* bias; float* C;
  int M, Kd, ldc, m0, transC;
  if (by < 13) { A = v; W = Wv; bias = bv; C = vpT; M = 800;  Kd = 1024; ldc = LDC_VT; m0 = by * 64;        transC = 1; }
  else         { A = q; W = Wq; bias = bq; C = qp;  M = 4096; Kd = 768;  ldc = 512;    m0 = (by - 13) * 64; transC = 0; }
  const int n0 = blockIdx.x * 64;

  const int lane = t & 63;
  const int wave = t >> 6;
  const int wm   = wave >> 1;
  const int wn   = wave & 1;
  const int la   = lane & 15;
  const int lb   = lane >> 4;

  // staging assignment: thread -> (row srow, 16-wide k slice at skq)
  const int srow = t >> 2;
  const int skq  = (t & 3) * 16;

  int gr = m0 + srow; if (gr >= M) gr = M - 1;     // clamp; store-side guarded
  const float* Arow = A + (size_t)gr * Kd + skq;
  const float* Wrow = W + (size_t)(n0 + srow) * Kd + skq;

  f32x4 acc[2][2] = {};
  f32x4 raA[4], rbA[4], raB[4], rbB[4];

  auto loadG = [&](f32x4* ra, f32x4* rb, int s) {
    const float* ap = Arow + s * 64;
    const float* wp = Wrow + s * 64;
#pragma unroll
    for (int i = 0; i < 4; ++i) ra[i] = *(const f32x4*)&ap[i * 4];
#pragma unroll
    for (int i = 0; i < 4; ++i) rb[i] = *(const f32x4*)&wp[i * 4];
  };

  const int o0 = (srow * 128 + skq * 2)      ^ ((srow & 7) << 4);
  const int o1 = (srow * 128 + skq * 2 + 16) ^ ((srow & 7) << 4);

  auto writeL = [&](unsigned short* da, unsigned short* db,
                    const f32x4* ra, const f32x4* rb) {
    u32x4 p;
    p[0] = cvtpk(ra[0][0], ra[0][1]); p[1] = cvtpk(ra[0][2], ra[0][3]);
    p[2] = cvtpk(ra[1][0], ra[1][1]); p[3] = cvtpk(ra[1][2], ra[1][3]);
    *(u32x4*)((char*)da + o0) = p;
    p[0] = cvtpk(ra[2][0], ra[2][1]); p[1] = cvtpk(ra[2][2], ra[2][3]);
    p[2] = cvtpk(ra[3][0], ra[3][1]); p[3] = cvtpk(ra[3][2], ra[3][3]);
    *(u32x4*)((char*)da + o1) = p;
    p[0] = cvtpk(rb[0][0], rb[0][1]); p[1] = cvtpk(rb[0][2], rb[0][3]);
    p[2] = cvtpk(rb[1][0], rb[1][1]); p[3] = cvtpk(rb[1][2], rb[1][3]);
    *(u32x4*)((char*)db + o0) = p;
    p[0] = cvtpk(rb[2][0], rb[2][1]); p[1] = cvtpk(rb[2][2], rb[2][3]);
    p[2] = cvtpk(rb[3][0], rb[3][1]); p[3] = cvtpk(rb[3][2], rb[3][3]);
    *(u32x4*)((char*)db + o1) = p;
  };

  auto compute = [&](const unsigned short* sa, const unsigned short* sb) {
    bfrag af[2][2], bf[2][2];
#pragma unroll
    for (int r = 0; r < 2; ++r)
#pragma unroll
      for (int kk = 0; kk < 2; ++kk) {
        int rowa = wm * 32 + r * 16 + la;
        af[r][kk] = *(const bfrag*)((const char*)sa +
                     ((rowa * 128 + kk * 64 + lb * 16) ^ ((rowa & 7) << 4)));
        int rowb = wn * 32 + r * 16 + la;
        bf[r][kk] = *(const bfrag*)((const char*)sb +
                     ((rowb * 128 + kk * 64 + lb * 16) ^ ((rowb & 7) << 4)));
      }
#pragma unroll
    for (int kk = 0; kk < 2; ++kk)
#pragma unroll
      for (int r = 0; r < 2; ++r)
#pragma unroll
        for (int c = 0; c < 2; ++c)
          acc[r][c] = __builtin_amdgcn_mfma_f32_16x16x32_bf16(af[r][kk], bf[c][kk], acc[r][c], 0, 0, 0);
  };

  // pipeline: nsteps is even for both paths (16 / 12)
  const int nsteps = Kd >> 6;
  loadG(raA, rbA, 0);
  writeL(As[0], Bs[0], raA, rbA);
  loadG(raB, rbB, 1);
  __syncthreads();
  for (int s = 0; s < nsteps; s += 2) {
    if (s + 2 < nsteps) loadG(raA, rbA, s + 2);
    compute(As[0], Bs[0]);
    writeL(As[1], Bs[1], raB, rbB);
    __syncthreads();
    if (s + 3 < nsteps) loadG(raB, rbB, s + 3);
    compute(As[1], Bs[1]);
    if (s + 2 < nsteps) writeL(As[0], Bs[0], raA, rbA);
    __syncthreads();
  }

  const float CEXP = 2.885390081777927f;   // 2*log2(e)
#pragma unroll
  for (int c = 0; c < 2; ++c) {
    int col = n0 + wn * 32 + c * 16 + la;
    float bcol = bias[col];
#pragma unroll
    for (int r = 0; r < 2; ++r) {
      int mbase = m0 + wm * 32 + r * 16 + lb * 4;
      if (transC) {
        if (mbase + 3 < M) {
          f32x4 o;
#pragma unroll
          for (int e = 0; e < 4; ++e)
            o[e] = __builtin_amdgcn_exp2f((acc[r][c][e] + bcol) * CEXP);
          *(f32x4*)&C[(size_t)col * ldc + mbase] = o;
        } else {
#pragma unroll
          for (int e = 0; e < 4; ++e)
            if (mbase + e < M)
              C[(size_t)col * ldc + mbase + e] =
                  __builtin_amdgcn_exp2f((acc[r][c][e] + bcol) * CEXP);
        }
      } else {
#pragma unroll
        for (int e = 0; e < 4; ++e)
          C[(size_t)(mbase + e) * ldc + col] =
              __builtin_amdgcn_exp2f((acc[r][c][e] + bcol) * CEXP);
      }
    }
  }
}

// ---------------------------------------------------------------------------
// Stage 3: logits + masked softmax. grid (32 chunks, 16 b), 512 thr = 8 waves.
// Wave = one row, lane = box k. Ev_T staged via global_load_lds into
// vpS[h][64] (stride 64 -> 2-way = free). 64-h chunks, double-buffered:
// chunk c+1's loads issued before computing chunk c; one barrier per chunk.
// Inner op: denom = fma(Ev,Eq,1); acc = fma(wl, rcp(denom), acc).
// ---------------------------------------------------------------------------
__global__ void __launch_bounds__(512) stage3_kernel(
    const float* __restrict__ vpT, const float* __restrict__ qp,
    const float* __restrict__ wl,  const int* __restrict__ box_mask,
    float* __restrict__ out) {
  __shared__ float vpS[2][64][64];   // 32 KB
  __shared__ float qpS[2][8][64];    //  4 KB
  __shared__ float wlS[2][64];       // .5 KB

  const int b     = blockIdx.y;
  const int chunk = blockIdx.x;            // 0..31
  const int t     = threadIdx.x;
  const int wv    = t >> 6;                // 0..7: wave = row-in-block
  const int k     = t & 63;                // box id
  const int rowg  = b * 256 + chunk * 8 + wv;
  const float* qrow = qp + (size_t)rowg * 512;

  auto STAGE = [&](int buf, int h0) {
#pragma unroll
    for (int i = 0; i < 8; ++i) {
      int hh = wv * 8 + i;
      gload4(vpT + (size_t)(h0 + hh) * LDC_VT + b * 50 + k, &vpS[buf][hh][0]);
    }
    gload4(qrow + h0 + k, &qpS[buf][wv][0]);
    if (wv == 0) gload4(wl + h0 + k, &wlS[buf][0]);
  };

  float a0 = 0.f, a1 = 0.f, a2 = 0.f, a3 = 0.f;

  STAGE(0, 0);
  __syncthreads();
  int buf = 0;
  for (int c = 0; c < 8; ++c) {
    if (c < 7) STAGE(buf ^ 1, (c + 1) * 64);
#pragma unroll 4
    for (int hh = 0; hh < 64; hh += 4) {
      f32x4 q4 = *(const f32x4*)&qpS[buf][wv][hh];   // wave-uniform broadcast
      f32x4 w4 = *(const f32x4*)&wlS[buf][hh];       // broadcast
      float v0 = vpS[buf][hh + 0][k];
      float v1 = vpS[buf][hh + 1][k];
      float v2 = vpS[buf][hh + 2][k];
      float v3 = vpS[buf][hh + 3][k];
      a0 = fmaf(w4[0], __builtin_amdgcn_rcpf(fmaf(v0, q4[0], 1.f)), a0);
      a1 = fmaf(w4[1], __builtin_amdgcn_rcpf(fmaf(v1, q4[1], 1.f)), a1);
      a2 = fmaf(w4[2], __builtin_amdgcn_rcpf(fmaf(v2, q4[2], 1.f)), a2);
      a3 = fmaf(w4[3], __builtin_amdgcn_rcpf(fmaf(v3, q4[3], 1.f)), a3);
    }
    __syncthreads();   // drains vmcnt(0): chunk c+1 staged, buf^1 safe to reuse
    buf ^= 1;
  }

  float logit = -2.f * ((a0 + a1) + (a2 + a3));

  // masked softmax over lanes 0..49
  int   msk = (k < 50) ? box_mask[b * 50 + k] : 0;
  float l   = (k < 50 && msk > 0) ? logit : -1e9f;

  float mx = l;
#pragma unroll
  for (int off = 32; off; off >>= 1) mx = fmaxf(mx, __shfl_xor(mx, off));
  float e = (k < 50) ? __builtin_amdgcn_exp2f((l - mx) * 1.4426950408889634f) : 0.f;
  float s = e;
#pragma unroll
  for (int off = 32; off; off >>= 1) s += __shfl_xor(s, off);

  if (k < 50) out[(size_t)rowg * 50 + k] = e / s;
}

// ---------------------------------------------------------------------------
// launch
// ---------------------------------------------------------------------------
extern "C" void kernel_launch(void* const* d_in, const int* in_sizes, int n_in,
                              void* d_out, int out_size, void* d_ws, size_t ws_size,
                              hipStream_t stream) {
  const float* v        = (const float*)d_in[0];
  const float* q        = (const float*)d_in[1];
  const int*   box_mask = (const int*)d_in[2];
  // d_in[3] = tags_attention (unused by reference)
  const float* Wv       = (const float*)d_in[4];
  const float* bv       = (const float*)d_in[5];
  const float* Wq       = (const float*)d_in[6];
  const float* bq       = (const float*)d_in[7];
  const float* Wl       = (const float*)d_in[8];
  // d_in[9] = bl (softmax-invariant, and zero)
  float* out = (float*)d_out;

  char* ws = (char*)d_ws;
  float* vpT = (float*)(ws);             // 512*832*4  = 1,703,936 B  (holds Ev_T)
  float* qp  = (float*)(ws + 1703936);   // 4096*512*4 = 8,388,608 B  (holds Eq)

  gemm_fused<<<dim3(8, 77),  256, 0, stream>>>(v, q, Wv, bv, Wq, bq, vpT, qp);
  stage3_kernel<<<dim3(32, 16), 512, 0, stream>>>(vpT, qp, Wl, box_mask, out);
}

// Round 6
// 54.351 us; speedup vs baseline: 2.3279x; 1.0406x over previous
//
#include <hip/hip_runtime.h>
#include <hip/hip_bf16.h>
#include <cstddef>

// ---------------------------------------------------------------------------
// B=16, N=4, S=64, K=50, VD=1024, QD=768, H=512; ROWS = B*N*S = 4096
//   Ev[k_glob][h] = exp2(CEXP*(v[b,k,:] .Wv[h,:] + bv[h]))   (row-major)
//   Eq[row][h]    = exp2(CEXP*(q[row,:] .Wq[h,:] + bq[h]))
//   logit[row][k] = -2 * sum_h wl[h] * rcp(Ev[k][h]*Eq[row][h] + 1)
//     (tanh(x) = 1 - 2/(e^{2x}+1); exp2 factorized into the projection
//      spaces; k-uniform sum_h wl dropped: softmax-invariant; CEXP=2*log2e)
//   out = masked softmax over k (50 boxes)
// ---------------------------------------------------------------------------

typedef __attribute__((ext_vector_type(4))) float        f32x4;
typedef __attribute__((ext_vector_type(8))) short        bfrag;   // 8 bf16
typedef __attribute__((ext_vector_type(4))) unsigned int u32x4;

__device__ __forceinline__ void gload4(const float* g, float* l) {
  __builtin_amdgcn_global_load_lds((const __attribute__((address_space(1))) void*)g,
                                   (__attribute__((address_space(3))) void*)l, 4, 0, 0);
}

__device__ __forceinline__ unsigned int cvtpk(float a, float b) {
  unsigned int r;
  asm("v_cvt_pk_bf16_f32 %0, %1, %2" : "=v"(r) : "v"(a), "v"(b));
  return r;   // low16 = bf16(a), high16 = bf16(b)
}

// ---------------------------------------------------------------------------
// Fused GEMM, software-pipelined (2-deep reg lookahead + LDS double buffer).
// Block id decode groups all 8 n-tiles of one m-tile onto ONE XCD
// (id%8 == m%8; XCD = linear id % 8 round-robin): A-tile fetched once per
// XCD instead of 8x.
//   m in [0,13)  : v-proj  M=800,  Kd=1024, C = Ev  (row-major, ldc=512)
//   m in [13,77) : q-proj  M=4096, Kd=768,  C = Eq  (row-major, ldc=512)
// Tile 64(M) x 64(N), BK=64, 4 waves (2x2), wave tile 32x32.
// fp32->bf16 fused into staging (v_cvt_pk_bf16_f32). LDS XOR-swizzled:
// byte ^= (row&7)<<4  -> ds_write_b128 conflict-free, frag reads free.
// Epilogue stores exp2(CEXP*(acc+bias))  (the hoisted exp2 factor).
// ---------------------------------------------------------------------------
__global__ void __launch_bounds__(256) gemm_fused(
    const float* __restrict__ v,  const float* __restrict__ q,
    const float* __restrict__ Wv, const float* __restrict__ bv,
    const float* __restrict__ Wq, const float* __restrict__ bq,
    float* __restrict__ vpw, float* __restrict__ qpw) {
  __shared__ unsigned short As[2][64 * 64];   // 8 KB per buf
  __shared__ unsigned short Bs[2][64 * 64];

  const int id = blockIdx.x;
  const int m  = (id & 7) + ((id >> 6) << 3);   // m-tile index, 0..79
  const int nt = (id >> 3) & 7;                 // n-tile index, 0..7
  if (m >= 77) return;

  const int t = threadIdx.x;

  const float* A; const float* W; const float* bias; float* C;
  int M, Kd, m0;
  if (m < 13) { A = v; W = Wv; bias = bv; C = vpw; M = 800;  Kd = 1024; m0 = m * 64; }
  else        { A = q; W = Wq; bias = bq; C = qpw; M = 4096; Kd = 768;  m0 = (m - 13) * 64; }
  const int n0 = nt * 64;

  const int lane = t & 63;
  const int wave = t >> 6;
  const int wm   = wave >> 1;
  const int wn   = wave & 1;
  const int la   = lane & 15;
  const int lb   = lane >> 4;

  // staging assignment: thread -> (row srow, 16-wide k slice at skq)
  const int srow = t >> 2;
  const int skq  = (t & 3) * 16;

  int gr = m0 + srow; if (gr >= M) gr = M - 1;     // clamp; store-side guarded
  const float* Arow = A + (size_t)gr * Kd + skq;
  const float* Wrow = W + (size_t)(n0 + srow) * Kd + skq;

  f32x4 acc[2][2] = {};
  f32x4 raA[4], rbA[4], raB[4], rbB[4];

  auto loadG = [&](f32x4* ra, f32x4* rb, int s) {
    const float* ap = Arow + s * 64;
    const float* wp = Wrow + s * 64;
#pragma unroll
    for (int i = 0; i < 4; ++i) ra[i] = *(const f32x4*)&ap[i * 4];
#pragma unroll
    for (int i = 0; i < 4; ++i) rb[i] = *(const f32x4*)&wp[i * 4];
  };

  const int o0 = (srow * 128 + skq * 2)      ^ ((srow & 7) << 4);
  const int o1 = (srow * 128 + skq * 2 + 16) ^ ((srow & 7) << 4);

  auto writeL = [&](unsigned short* da, unsigned short* db,
                    const f32x4* ra, const f32x4* rb) {
    u32x4 p;
    p[0] = cvtpk(ra[0][0], ra[0][1]); p[1] = cvtpk(ra[0][2], ra[0][3]);
    p[2] = cvtpk(ra[1][0], ra[1][1]); p[3] = cvtpk(ra[1][2], ra[1][3]);
    *(u32x4*)((char*)da + o0) = p;
    p[0] = cvtpk(ra[2][0], ra[2][1]); p[1] = cvtpk(ra[2][2], ra[2][3]);
    p[2] = cvtpk(ra[3][0], ra[3][1]); p[3] = cvtpk(ra[3][2], ra[3][3]);
    *(u32x4*)((char*)da + o1) = p;
    p[0] = cvtpk(rb[0][0], rb[0][1]); p[1] = cvtpk(rb[0][2], rb[0][3]);
    p[2] = cvtpk(rb[1][0], rb[1][1]); p[3] = cvtpk(rb[1][2], rb[1][3]);
    *(u32x4*)((char*)db + o0) = p;
    p[0] = cvtpk(rb[2][0], rb[2][1]); p[1] = cvtpk(rb[2][2], rb[2][3]);
    p[2] = cvtpk(rb[3][0], rb[3][1]); p[3] = cvtpk(rb[3][2], rb[3][3]);
    *(u32x4*)((char*)db + o1) = p;
  };

  auto compute = [&](const unsigned short* sa, const unsigned short* sb) {
    bfrag af[2][2], bf[2][2];
#pragma unroll
    for (int r = 0; r < 2; ++r)
#pragma unroll
      for (int kk = 0; kk < 2; ++kk) {
        int rowa = wm * 32 + r * 16 + la;
        af[r][kk] = *(const bfrag*)((const char*)sa +
                     ((rowa * 128 + kk * 64 + lb * 16) ^ ((rowa & 7) << 4)));
        int rowb = wn * 32 + r * 16 + la;
        bf[r][kk] = *(const bfrag*)((const char*)sb +
                     ((rowb * 128 + kk * 64 + lb * 16) ^ ((rowb & 7) << 4)));
      }
#pragma unroll
    for (int kk = 0; kk < 2; ++kk)
#pragma unroll
      for (int r = 0; r < 2; ++r)
#pragma unroll
        for (int c = 0; c < 2; ++c)
          acc[r][c] = __builtin_amdgcn_mfma_f32_16x16x32_bf16(af[r][kk], bf[c][kk], acc[r][c], 0, 0, 0);
  };

  // pipeline: nsteps is even for both paths (16 / 12)
  const int nsteps = Kd >> 6;
  loadG(raA, rbA, 0);
  writeL(As[0], Bs[0], raA, rbA);
  loadG(raB, rbB, 1);
  __syncthreads();
  for (int s = 0; s < nsteps; s += 2) {
    if (s + 2 < nsteps) loadG(raA, rbA, s + 2);
    compute(As[0], Bs[0]);
    writeL(As[1], Bs[1], raB, rbB);
    __syncthreads();
    if (s + 3 < nsteps) loadG(raB, rbB, s + 3);
    compute(As[1], Bs[1]);
    if (s + 2 < nsteps) writeL(As[0], Bs[0], raA, rbA);
    __syncthreads();
  }

  const float CEXP = 2.885390081777927f;   // 2*log2(e)
#pragma unroll
  for (int c = 0; c < 2; ++c) {
    int col = n0 + wn * 32 + c * 16 + la;
    float bcol = bias[col];
#pragma unroll
    for (int r = 0; r < 2; ++r) {
      int mbase = m0 + wm * 32 + r * 16 + lb * 4;
#pragma unroll
      for (int e = 0; e < 4; ++e) {
        int mr = mbase + e;
        if (mr < M)
          C[(size_t)mr * 512 + col] =
              __builtin_amdgcn_exp2f((acc[r][c][e] + bcol) * CEXP);
      }
    }
  }
}

// ---------------------------------------------------------------------------
// Stage 3: logits + masked softmax. grid (32 chunks, 16 b), 512 thr = 8 waves.
// Wave = one row, lane = box k. Ev staged [k][h] with XOR-swizzled cols
// (col c holds h0 + (c ^ ((k&7)<<2))) via pre-swizzled global_load_lds source
// (linear LDS dest). Read: lane k does ONE ds_read_b128 per 4 h at
// byte = k*256 + ((hh<<2) ^ ((k&7)<<4)) — conflict-free (m214 pattern).
// 64-h chunks, double-buffered, one barrier per chunk.
// Inner op: acc = fma(wl, rcp(fma(Ev,Eq,1)), acc).
// ---------------------------------------------------------------------------
__global__ void __launch_bounds__(512) stage3_kernel(
    const float* __restrict__ vp, const float* __restrict__ qp,
    const float* __restrict__ wl, const int* __restrict__ box_mask,
    float* __restrict__ out) {
  __shared__ float vpS[2][50][64];   // 25.6 KB
  __shared__ float qpS[2][8][64];    //  4 KB
  __shared__ float wlS[2][64];       // .5 KB

  const int b     = blockIdx.y;
  const int chunk = blockIdx.x;            // 0..31
  const int t     = threadIdx.x;
  const int wv    = t >> 6;                // 0..7: wave = row-in-block
  const int k     = t & 63;                // box id (lane)
  const int rowg  = b * 256 + chunk * 8 + wv;
  const float* qrow = qp + (size_t)rowg * 512;

  const int kc = (k < 50) ? k : k - 14;    // lanes 50..63 duplicate 36..49 (broadcast)
  const int cb = kc * 256 + ((kc & 7) << 4);   // lane-const byte base (bits disjoint)
  const int lsrc = k ^ (wv << 2);          // staging source col (rows kr: kr&7 == wv)

  auto STAGE = [&](int buf, int h0) {
#pragma unroll
    for (int i = 0; i < 7; ++i) {
      int kr = i * 8 + wv;                 // kr & 7 == wv
      if (kr < 50)
        gload4(vp + (size_t)(b * 50 + kr) * 512 + h0 + lsrc, &vpS[buf][kr][0]);
    }
    gload4(qrow + h0 + k, &qpS[buf][wv][0]);
    if (wv == 0) gload4(wl + h0 + k, &wlS[buf][0]);
  };

  float a0 = 0.f, a1 = 0.f, a2 = 0.f, a3 = 0.f;

  STAGE(0, 0);
  __syncthreads();
  int buf = 0;
  for (int c = 0; c < 8; ++c) {
    if (c < 7) STAGE(buf ^ 1, (c + 1) * 64);
    const char* vb = (const char*)&vpS[buf][0][0];
#pragma unroll
    for (int hh = 0; hh < 64; hh += 4) {
      f32x4 v4 = *(const f32x4*)(vb + (cb ^ (hh << 2)));
      f32x4 q4 = *(const f32x4*)&qpS[buf][wv][hh];   // wave-uniform broadcast
      f32x4 w4 = *(const f32x4*)&wlS[buf][hh];       // broadcast
      a0 = fmaf(w4[0], __builtin_amdgcn_rcpf(fmaf(v4[0], q4[0], 1.f)), a0);
      a1 = fmaf(w4[1], __builtin_amdgcn_rcpf(fmaf(v4[1], q4[1], 1.f)), a1);
      a2 = fmaf(w4[2], __builtin_amdgcn_rcpf(fmaf(v4[2], q4[2], 1.f)), a2);
      a3 = fmaf(w4[3], __builtin_amdgcn_rcpf(fmaf(v4[3], q4[3], 1.f)), a3);
    }
    __syncthreads();   // drains vmcnt(0): chunk c+1 staged, buf^1 safe to reuse
    buf ^= 1;
  }

  float logit = -2.f * ((a0 + a1) + (a2 + a3));

  // masked softmax over lanes 0..49
  int   msk = (k < 50) ? box_mask[b * 50 + k] : 0;
  float l   = (k < 50 && msk > 0) ? logit : -1e9f;

  float mx = l;
#pragma unroll
  for (int off = 32; off; off >>= 1) mx = fmaxf(mx, __shfl_xor(mx, off));
  float e = (k < 50) ? __builtin_amdgcn_exp2f((l - mx) * 1.4426950408889634f) : 0.f;
  float s = e;
#pragma unroll
  for (int off = 32; off; off >>= 1) s += __shfl_xor(s, off);

  if (k < 50) out[(size_t)rowg * 50 + k] = e / s;
}

// ---------------------------------------------------------------------------
// launch
// ---------------------------------------------------------------------------
extern "C" void kernel_launch(void* const* d_in, const int* in_sizes, int n_in,
                              void* d_out, int out_size, void* d_ws, size_t ws_size,
                              hipStream_t stream) {
  const float* v        = (const float*)d_in[0];
  const float* q        = (const float*)d_in[1];
  const int*   box_mask = (const int*)d_in[2];
  // d_in[3] = tags_attention (unused by reference)
  const float* Wv       = (const float*)d_in[4];
  const float* bv       = (const float*)d_in[5];
  const float* Wq       = (const float*)d_in[6];
  const float* bq       = (const float*)d_in[7];
  const float* Wl       = (const float*)d_in[8];
  // d_in[9] = bl (softmax-invariant, and zero)
  float* out = (float*)d_out;

  char* ws = (char*)d_ws;
  float* vpw = (float*)(ws);             // 800*512*4  = 1,638,400 B  (holds Ev)
  float* qpw = (float*)(ws + 1638400);   // 4096*512*4 = 8,388,608 B  (holds Eq)

  gemm_fused<<<dim3(640),   256, 0, stream>>>(v, q, Wv, bv, Wq, bq, vpw, qpw);
  stage3_kernel<<<dim3(32, 16), 512, 0, stream>>>(vpw, qpw, Wl, box_mask, out);
}